// Round 1
// baseline (44.201 us; speedup 1.0000x reference)
//
#include <hip/hip_runtime.h>
#include <hip/hip_fp16.h>

// Problem constants (fixed by the reference): Cl(3,0), B=4, S=1024, 8 components.
#define SEQ 1024
#define BATCH 4

// ---------------------------------------------------------------------------
// Compile-time Cayley table for Cl(3,0), basis sorted by (grade, lex):
// masks = [0,1,2,4,3,5,6,7].  For each (i,k): e_i * e_k = s[i][k] * e_{j[i][k]}.
// ---------------------------------------------------------------------------
struct CayTab { int j[8][8]; float s[8][8]; };

constexpr CayTab build_tab() {
  CayTab t{};
  int masks[8] = {0, 1, 2, 4, 3, 5, 6, 7};
  int idx[8]   = {0, 0, 0, 0, 0, 0, 0, 0};
  for (int p = 0; p < 8; ++p) idx[masks[p]] = p;
  for (int i = 0; i < 8; ++i) {
    for (int k = 0; k < 8; ++k) {
      int a = masks[i], bm = masks[k];
      int swaps = 0;
      int tt = a >> 1;
      while (tt) {
        int u = tt & bm;
        while (u) { swaps += u & 1; u >>= 1; }
        tt >>= 1;
      }
      t.j[i][k] = idx[a ^ bm];
      t.s[i][k] = (swaps & 1) ? -1.0f : 1.0f;  // metric = (+1,+1,+1)
    }
  }
  return t;
}
constexpr CayTab CAY = build_tab();

union H8 { float4 f4; __half h[8]; };

// ---------------------------------------------------------------------------
// Kernel 1: q/k = LN(mvlinear(x, W, b)) rounded to f16.
// Grid: SEQ blocks (one per output row n). Block: 256 threads = 4 waves.
// Wave w handles batch b = w, computing both q[b,n,:] and k[b,n,:].
// out[b,n,i] = sum_m x[b,m,i] * W[n,m,g(i)],  g = [0,1,1,1,2,2,2,3].
// ---------------------------------------------------------------------------
__global__ __launch_bounds__(256) void qk_kernel(
    const float* __restrict__ x,      // [B, S, 8]
    const float* __restrict__ Wq,     // [S, S, 4]
    const float* __restrict__ bq,     // [S]
    const float* __restrict__ Wk,     // [S, S, 4]
    const float* __restrict__ bk,     // [S]
    const float* __restrict__ gamma,  // [8]
    const float* __restrict__ beta,   // [8]
    __half* __restrict__ qout,        // [B, S, 8]
    __half* __restrict__ kout)        // [B, S, 8]
{
  const int n    = blockIdx.x;
  const int b    = threadIdx.x >> 6;   // wave id = batch
  const int lane = threadIdx.x & 63;

  const float* xb = x  + (size_t)b * SEQ * 8;
  const float* wq = Wq + (size_t)n * SEQ * 4;
  const float* wk = Wk + (size_t)n * SEQ * 4;

  float aq[8], ak[8];
#pragma unroll
  for (int i = 0; i < 8; ++i) { aq[i] = 0.0f; ak[i] = 0.0f; }

  for (int m = lane; m < SEQ; m += 64) {
    float4 x0 = *(const float4*)(xb + (size_t)m * 8);
    float4 x1 = *(const float4*)(xb + (size_t)m * 8 + 4);
    float4 q4 = *(const float4*)(wq + (size_t)m * 4);
    float4 k4 = *(const float4*)(wk + (size_t)m * 4);

    aq[0] = fmaf(x0.x, q4.x, aq[0]);
    aq[1] = fmaf(x0.y, q4.y, aq[1]);
    aq[2] = fmaf(x0.z, q4.y, aq[2]);
    aq[3] = fmaf(x0.w, q4.y, aq[3]);
    aq[4] = fmaf(x1.x, q4.z, aq[4]);
    aq[5] = fmaf(x1.y, q4.z, aq[5]);
    aq[6] = fmaf(x1.z, q4.z, aq[6]);
    aq[7] = fmaf(x1.w, q4.w, aq[7]);

    ak[0] = fmaf(x0.x, k4.x, ak[0]);
    ak[1] = fmaf(x0.y, k4.y, ak[1]);
    ak[2] = fmaf(x0.z, k4.y, ak[2]);
    ak[3] = fmaf(x0.w, k4.y, ak[3]);
    ak[4] = fmaf(x1.x, k4.z, ak[4]);
    ak[5] = fmaf(x1.y, k4.z, ak[5]);
    ak[6] = fmaf(x1.z, k4.z, ak[6]);
    ak[7] = fmaf(x1.w, k4.w, ak[7]);
  }

  // 64-lane butterfly reduction (all lanes end with the full sums).
#pragma unroll
  for (int off = 32; off >= 1; off >>= 1) {
#pragma unroll
    for (int i = 0; i < 8; ++i) {
      aq[i] += __shfl_xor(aq[i], off, 64);
      ak[i] += __shfl_xor(ak[i], off, 64);
    }
  }

  if (lane == 0) {
    aq[0] += bq[n];   // bias on scalar component only
    ak[0] += bk[n];

    // LayerNorm + f16 round + store, for q then k.
    {
      float mu = 0.0f;
#pragma unroll
      for (int i = 0; i < 8; ++i) mu += aq[i];
      mu *= 0.125f;
      float var = 0.0f;
#pragma unroll
      for (int i = 0; i < 8; ++i) { float d = aq[i] - mu; var = fmaf(d, d, var); }
      var *= 0.125f;
      float inv = rsqrtf(var + 1e-5f);
      H8 u;
#pragma unroll
      for (int i = 0; i < 8; ++i)
        u.h[i] = __float2half((aq[i] - mu) * inv * gamma[i] + beta[i]);
      *(float4*)(qout + ((size_t)b * SEQ + n) * 8) = u.f4;
    }
    {
      float mu = 0.0f;
#pragma unroll
      for (int i = 0; i < 8; ++i) mu += ak[i];
      mu *= 0.125f;
      float var = 0.0f;
#pragma unroll
      for (int i = 0; i < 8; ++i) { float d = ak[i] - mu; var = fmaf(d, d, var); }
      var *= 0.125f;
      float inv = rsqrtf(var + 1e-5f);
      H8 u;
#pragma unroll
      for (int i = 0; i < 8; ++i)
        u.h[i] = __float2half((ak[i] - mu) * inv * gamma[i] + beta[i]);
      *(float4*)(kout + ((size_t)b * SEQ + n) * 8) = u.f4;
    }
  }
}

// ---------------------------------------------------------------------------
// Kernel 2: out[b,n,m,j] = sum_{i,k} q[b,n,i] * C[i,j,k] * k[b,m,k]
// One thread per (b,n,m): 16B q load (broadcast), 16B k load (coalesced),
// 64 constant-folded FMAs, 32B contiguous f32 store.
// ---------------------------------------------------------------------------
__global__ __launch_bounds__(256) void gp_kernel(
    const __half* __restrict__ q,   // [B, S, 8]
    const __half* __restrict__ k,   // [B, S, 8]
    float* __restrict__ out)        // [B, S, S, 8]
{
  const int tid = blockIdx.x * 256 + threadIdx.x;  // b*S*S + n*S + m
  const int m   = tid & (SEQ - 1);
  const int bn  = tid >> 10;        // b*S + n
  const int b   = bn >> 10;

  H8 uq, uk;
  uq.f4 = *(const float4*)(q + (size_t)bn * 8);
  uk.f4 = *(const float4*)(k + ((size_t)b * SEQ + m) * 8);

  float qf[8], kf[8];
#pragma unroll
  for (int i = 0; i < 8; ++i) {
    qf[i] = __half2float(uq.h[i]);
    kf[i] = __half2float(uk.h[i]);
  }

  float o[8] = {0, 0, 0, 0, 0, 0, 0, 0};
#pragma unroll
  for (int i = 0; i < 8; ++i) {
#pragma unroll
    for (int kk = 0; kk < 8; ++kk) {
      o[CAY.j[i][kk]] = fmaf(CAY.s[i][kk] * qf[i], kf[kk], o[CAY.j[i][kk]]);
    }
  }

  float4* dst = (float4*)(out + (size_t)tid * 8);
  dst[0] = make_float4(o[0], o[1], o[2], o[3]);
  dst[1] = make_float4(o[4], o[5], o[6], o[7]);
}

// ---------------------------------------------------------------------------
extern "C" void kernel_launch(void* const* d_in, const int* in_sizes, int n_in,
                              void* d_out, int out_size, void* d_ws, size_t ws_size,
                              hipStream_t stream) {
  const float* x     = (const float*)d_in[0];
  const float* Wq    = (const float*)d_in[1];
  const float* bq    = (const float*)d_in[2];
  const float* Wk    = (const float*)d_in[3];
  const float* bk    = (const float*)d_in[4];
  const float* gamma = (const float*)d_in[5];
  const float* beta  = (const float*)d_in[6];

  __half* qbuf = (__half*)d_ws;
  __half* kbuf = qbuf + (size_t)BATCH * SEQ * 8;

  qk_kernel<<<SEQ, 256, 0, stream>>>(x, Wq, bq, Wk, bk, gamma, beta, qbuf, kbuf);

  const int total = BATCH * SEQ * SEQ;               // threads = one per (b,n,m)
  gp_kernel<<<total / 256, 256, 0, stream>>>(qbuf, kbuf, (float*)d_out);
}

// Round 2
// 42.582 us; speedup vs baseline: 1.0380x; 1.0380x over previous
//
#include <hip/hip_runtime.h>
#include <hip/hip_fp16.h>

// Problem constants (fixed by the reference): Cl(3,0), B=4, S=1024, 8 components.
#define SEQ 1024
#define BATCH 4

// ---------------------------------------------------------------------------
// Compile-time Cayley table for Cl(3,0), basis sorted by (grade, lex):
// masks = [0,1,2,4,3,5,6,7].  For each (i,k): e_i * e_k = s[i][k] * e_{j[i][k]}.
// ---------------------------------------------------------------------------
struct CayTab { int j[8][8]; float s[8][8]; };

constexpr CayTab build_tab() {
  CayTab t{};
  int masks[8] = {0, 1, 2, 4, 3, 5, 6, 7};
  int idx[8]   = {0, 0, 0, 0, 0, 0, 0, 0};
  for (int p = 0; p < 8; ++p) idx[masks[p]] = p;
  for (int i = 0; i < 8; ++i) {
    for (int k = 0; k < 8; ++k) {
      int a = masks[i], bm = masks[k];
      int swaps = 0;
      int tt = a >> 1;
      while (tt) {
        int u = tt & bm;
        while (u) { swaps += u & 1; u >>= 1; }
        tt >>= 1;
      }
      t.j[i][k] = idx[a ^ bm];
      t.s[i][k] = (swaps & 1) ? -1.0f : 1.0f;  // metric = (+1,+1,+1)
    }
  }
  return t;
}
constexpr CayTab CAY = build_tab();

union H8 { float4 f4; __half h[8]; };

// ---------------------------------------------------------------------------
// Kernel 1: q/k = LN(mvlinear(x, W, b)) rounded to f16.
// Grid: SEQ blocks (one per output row n). Block: 256 threads = 4 waves.
// Wave w handles batch b = w, computing both q[b,n,:] and k[b,n,:].
// out[b,n,i] = sum_m x[b,m,i] * W[n,m,g(i)],  g = [0,1,1,1,2,2,2,3].
// Weight rows (Wq[n,:,:], Wk[n,:,:]) are staged in LDS once per block and
// reused by all 4 waves (was: 4x redundant streaming reads per block).
// ---------------------------------------------------------------------------
__global__ __launch_bounds__(256) void qk_kernel(
    const float* __restrict__ x,      // [B, S, 8]
    const float* __restrict__ Wq,     // [S, S, 4]
    const float* __restrict__ bq,     // [S]
    const float* __restrict__ Wk,     // [S, S, 4]
    const float* __restrict__ bk,     // [S]
    const float* __restrict__ gamma,  // [8]
    const float* __restrict__ beta,   // [8]
    __half* __restrict__ qout,        // [B, S, 8]
    __half* __restrict__ kout)        // [B, S, 8]
{
  __shared__ float4 lds[2048];        // [0..1023] = Wq row, [1024..2047] = Wk row (32 KB)

  const int n    = blockIdx.x;
  const int b    = threadIdx.x >> 6;   // wave id = batch
  const int lane = threadIdx.x & 63;

  // Cooperative stage: both 16 KB weight rows -> LDS.
  {
    const float4* wq4 = (const float4*)(Wq + (size_t)n * SEQ * 4);
    const float4* wk4 = (const float4*)(Wk + (size_t)n * SEQ * 4);
#pragma unroll
    for (int t = 0; t < 4; ++t) {
      int idx = threadIdx.x + t * 256;
      lds[idx]        = wq4[idx];
      lds[1024 + idx] = wk4[idx];
    }
  }
  __syncthreads();

  const float* xb = x + (size_t)b * SEQ * 8;

  float aq[8], ak[8];
#pragma unroll
  for (int i = 0; i < 8; ++i) { aq[i] = 0.0f; ak[i] = 0.0f; }

  for (int m = lane; m < SEQ; m += 64) {
    float4 x0 = *(const float4*)(xb + (size_t)m * 8);
    float4 x1 = *(const float4*)(xb + (size_t)m * 8 + 4);
    float4 q4 = lds[m];
    float4 k4 = lds[1024 + m];

    aq[0] = fmaf(x0.x, q4.x, aq[0]);
    aq[1] = fmaf(x0.y, q4.y, aq[1]);
    aq[2] = fmaf(x0.z, q4.y, aq[2]);
    aq[3] = fmaf(x0.w, q4.y, aq[3]);
    aq[4] = fmaf(x1.x, q4.z, aq[4]);
    aq[5] = fmaf(x1.y, q4.z, aq[5]);
    aq[6] = fmaf(x1.z, q4.z, aq[6]);
    aq[7] = fmaf(x1.w, q4.w, aq[7]);

    ak[0] = fmaf(x0.x, k4.x, ak[0]);
    ak[1] = fmaf(x0.y, k4.y, ak[1]);
    ak[2] = fmaf(x0.z, k4.y, ak[2]);
    ak[3] = fmaf(x0.w, k4.y, ak[3]);
    ak[4] = fmaf(x1.x, k4.z, ak[4]);
    ak[5] = fmaf(x1.y, k4.z, ak[5]);
    ak[6] = fmaf(x1.z, k4.z, ak[6]);
    ak[7] = fmaf(x1.w, k4.w, ak[7]);
  }

  // Reduction. Step 1 (xor 1) also splits the work: even lanes carry the
  // q partials, odd lanes the k partials -> remaining 5 steps reduce 8
  // values instead of 16 (112 shuffle/add ops vs 192).
  float v[8];
  const bool odd = (lane & 1) != 0;
#pragma unroll
  for (int i = 0; i < 8; ++i) {
    float tq = __shfl_xor(aq[i], 1, 64);
    float tk = __shfl_xor(ak[i], 1, 64);
    v[i] = odd ? (ak[i] + tk) : (aq[i] + tq);
  }
#pragma unroll
  for (int off = 2; off < 64; off <<= 1) {
#pragma unroll
    for (int i = 0; i < 8; ++i) v[i] += __shfl_xor(v[i], off, 64);
  }

  // Lane 0 finishes q, lane 1 finishes k (parallel LN epilogues).
  if (lane < 2) {
    v[0] += odd ? bk[n] : bq[n];   // bias on scalar component only

    float mu = 0.0f;
#pragma unroll
    for (int i = 0; i < 8; ++i) mu += v[i];
    mu *= 0.125f;
    float var = 0.0f;
#pragma unroll
    for (int i = 0; i < 8; ++i) { float d = v[i] - mu; var = fmaf(d, d, var); }
    var *= 0.125f;
    float inv = rsqrtf(var + 1e-5f);

    H8 u;
#pragma unroll
    for (int i = 0; i < 8; ++i)
      u.h[i] = __float2half((v[i] - mu) * inv * gamma[i] + beta[i]);

    __half* dst = odd ? kout : qout;
    *(float4*)(dst + ((size_t)b * SEQ + n) * 8) = u.f4;
  }
}

// ---------------------------------------------------------------------------
// Kernel 2: out[b,n,m,j] = sum_{i,k} q[b,n,i] * C[i,j,k] * k[b,m,k]
// One thread per (b,n,m): 16B q load (broadcast), 16B k load (coalesced),
// 64 constant-folded FMAs, 32B contiguous f32 store.  Write-BW bound.
// ---------------------------------------------------------------------------
__global__ __launch_bounds__(256) void gp_kernel(
    const __half* __restrict__ q,   // [B, S, 8]
    const __half* __restrict__ k,   // [B, S, 8]
    float* __restrict__ out)        // [B, S, S, 8]
{
  const int tid = blockIdx.x * 256 + threadIdx.x;  // b*S*S + n*S + m
  const int m   = tid & (SEQ - 1);
  const int bn  = tid >> 10;        // b*S + n
  const int b   = bn >> 10;

  H8 uq, uk;
  uq.f4 = *(const float4*)(q + (size_t)bn * 8);
  uk.f4 = *(const float4*)(k + ((size_t)b * SEQ + m) * 8);

  float qf[8], kf[8];
#pragma unroll
  for (int i = 0; i < 8; ++i) {
    qf[i] = __half2float(uq.h[i]);
    kf[i] = __half2float(uk.h[i]);
  }

  float o[8] = {0, 0, 0, 0, 0, 0, 0, 0};
#pragma unroll
  for (int i = 0; i < 8; ++i) {
#pragma unroll
    for (int kk = 0; kk < 8; ++kk) {
      o[CAY.j[i][kk]] = fmaf(CAY.s[i][kk] * qf[i], kf[kk], o[CAY.j[i][kk]]);
    }
  }

  float4* dst = (float4*)(out + (size_t)tid * 8);
  dst[0] = make_float4(o[0], o[1], o[2], o[3]);
  dst[1] = make_float4(o[4], o[5], o[6], o[7]);
}

// ---------------------------------------------------------------------------
extern "C" void kernel_launch(void* const* d_in, const int* in_sizes, int n_in,
                              void* d_out, int out_size, void* d_ws, size_t ws_size,
                              hipStream_t stream) {
  const float* x     = (const float*)d_in[0];
  const float* Wq    = (const float*)d_in[1];
  const float* bq    = (const float*)d_in[2];
  const float* Wk    = (const float*)d_in[3];
  const float* bk    = (const float*)d_in[4];
  const float* gamma = (const float*)d_in[5];
  const float* beta  = (const float*)d_in[6];

  __half* qbuf = (__half*)d_ws;
  __half* kbuf = qbuf + (size_t)BATCH * SEQ * 8;

  qk_kernel<<<SEQ, 256, 0, stream>>>(x, Wq, bq, Wk, bk, gamma, beta, qbuf, kbuf);

  const int total = BATCH * SEQ * SEQ;               // threads = one per (b,n,m)
  gp_kernel<<<total / 256, 256, 0, stream>>>(qbuf, kbuf, (float*)d_out);
}

// Round 3
// 41.202 us; speedup vs baseline: 1.0728x; 1.0335x over previous
//
#include <hip/hip_runtime.h>
#include <hip/hip_fp16.h>

// Problem constants (fixed by the reference): Cl(3,0), B=4, S=1024, 8 components.
#define SEQ 1024
#define BATCH 4

// ---------------------------------------------------------------------------
// Compile-time inverse Cayley table for Cl(3,0), basis sorted by (grade, lex):
// masks = [0,1,2,4,3,5,6,7].  For each output component j there are exactly 8
// contributing pairs: out[j] = sum_c s[j][c] * q[qi[j][c]] * k[ki[j][c]].
// ---------------------------------------------------------------------------
struct InvTab { int qi[8][8]; int ki[8][8]; float s[8][8]; };

constexpr InvTab build_inv() {
  InvTab v{};
  int masks[8] = {0, 1, 2, 4, 3, 5, 6, 7};
  int idx[8]   = {0, 0, 0, 0, 0, 0, 0, 0};
  for (int p = 0; p < 8; ++p) idx[masks[p]] = p;
  int cnt[8] = {0, 0, 0, 0, 0, 0, 0, 0};
  for (int i = 0; i < 8; ++i) {
    for (int k = 0; k < 8; ++k) {
      int a = masks[i], bm = masks[k];
      int swaps = 0;
      int tt = a >> 1;
      while (tt) {
        int u = tt & bm;
        while (u) { swaps += u & 1; u >>= 1; }
        tt >>= 1;
      }
      int j = idx[a ^ bm];
      int c = cnt[j]++;
      v.qi[j][c] = i;
      v.ki[j][c] = k;
      v.s[j][c]  = (swaps & 1) ? -1.0f : 1.0f;  // metric = (+1,+1,+1)
    }
  }
  return v;
}
constexpr InvTab INV = build_inv();

union H8 { float4 f4; __half h[8]; };

// ---------------------------------------------------------------------------
// Kernel 1: q/k = LN(mvlinear(x, W, b)) rounded to f16.  (unchanged)
// ---------------------------------------------------------------------------
__global__ __launch_bounds__(256) void qk_kernel(
    const float* __restrict__ x,      // [B, S, 8]
    const float* __restrict__ Wq,     // [S, S, 4]
    const float* __restrict__ bq,     // [S]
    const float* __restrict__ Wk,     // [S, S, 4]
    const float* __restrict__ bk,     // [S]
    const float* __restrict__ gamma,  // [8]
    const float* __restrict__ beta,   // [8]
    __half* __restrict__ qout,        // [B, S, 8]
    __half* __restrict__ kout)        // [B, S, 8]
{
  __shared__ float4 lds[2048];        // [0..1023] = Wq row, [1024..2047] = Wk row (32 KB)

  const int n    = blockIdx.x;
  const int b    = threadIdx.x >> 6;   // wave id = batch
  const int lane = threadIdx.x & 63;

  // Cooperative stage: both 16 KB weight rows -> LDS.
  {
    const float4* wq4 = (const float4*)(Wq + (size_t)n * SEQ * 4);
    const float4* wk4 = (const float4*)(Wk + (size_t)n * SEQ * 4);
#pragma unroll
    for (int t = 0; t < 4; ++t) {
      int idx = threadIdx.x + t * 256;
      lds[idx]        = wq4[idx];
      lds[1024 + idx] = wk4[idx];
    }
  }
  __syncthreads();

  const float* xb = x + (size_t)b * SEQ * 8;

  float aq[8], ak[8];
#pragma unroll
  for (int i = 0; i < 8; ++i) { aq[i] = 0.0f; ak[i] = 0.0f; }

  for (int m = lane; m < SEQ; m += 64) {
    float4 x0 = *(const float4*)(xb + (size_t)m * 8);
    float4 x1 = *(const float4*)(xb + (size_t)m * 8 + 4);
    float4 q4 = lds[m];
    float4 k4 = lds[1024 + m];

    aq[0] = fmaf(x0.x, q4.x, aq[0]);
    aq[1] = fmaf(x0.y, q4.y, aq[1]);
    aq[2] = fmaf(x0.z, q4.y, aq[2]);
    aq[3] = fmaf(x0.w, q4.y, aq[3]);
    aq[4] = fmaf(x1.x, q4.z, aq[4]);
    aq[5] = fmaf(x1.y, q4.z, aq[5]);
    aq[6] = fmaf(x1.z, q4.z, aq[6]);
    aq[7] = fmaf(x1.w, q4.w, aq[7]);

    ak[0] = fmaf(x0.x, k4.x, ak[0]);
    ak[1] = fmaf(x0.y, k4.y, ak[1]);
    ak[2] = fmaf(x0.z, k4.y, ak[2]);
    ak[3] = fmaf(x0.w, k4.y, ak[3]);
    ak[4] = fmaf(x1.x, k4.z, ak[4]);
    ak[5] = fmaf(x1.y, k4.z, ak[5]);
    ak[6] = fmaf(x1.z, k4.z, ak[6]);
    ak[7] = fmaf(x1.w, k4.w, ak[7]);
  }

  // Reduction: step 1 (xor 1) splits q->even lanes, k->odd lanes.
  float v[8];
  const bool odd = (lane & 1) != 0;
#pragma unroll
  for (int i = 0; i < 8; ++i) {
    float tq = __shfl_xor(aq[i], 1, 64);
    float tk = __shfl_xor(ak[i], 1, 64);
    v[i] = odd ? (ak[i] + tk) : (aq[i] + tq);
  }
#pragma unroll
  for (int off = 2; off < 64; off <<= 1) {
#pragma unroll
    for (int i = 0; i < 8; ++i) v[i] += __shfl_xor(v[i], off, 64);
  }

  // Lane 0 finishes q, lane 1 finishes k (parallel LN epilogues).
  if (lane < 2) {
    v[0] += odd ? bk[n] : bq[n];   // bias on scalar component only

    float mu = 0.0f;
#pragma unroll
    for (int i = 0; i < 8; ++i) mu += v[i];
    mu *= 0.125f;
    float var = 0.0f;
#pragma unroll
    for (int i = 0; i < 8; ++i) { float d = v[i] - mu; var = fmaf(d, d, var); }
    var *= 0.125f;
    float inv = rsqrtf(var + 1e-5f);

    H8 u;
#pragma unroll
    for (int i = 0; i < 8; ++i)
      u.h[i] = __float2half((v[i] - mu) * inv * gamma[i] + beta[i]);

    __half* dst = odd ? kout : qout;
    *(float4*)(dst + ((size_t)b * SEQ + n) * 8) = u.f4;
  }
}

// ---------------------------------------------------------------------------
// Kernel 2: out[b,n,m,j] = sum_{i,k} q[b,n,i] * C[i,j,k] * k[b,m,k]
// TWO lanes per (b,n,m) point: half h = lane>>5 computes components 4h..4h+3
// (32 constant-folded FMAs via the inverse Cayley table).  Each lane stores
// ONE float4 at p*32 + h*16 -> every wave store instruction covers a fully
// dense, contiguous 1 KB (no partial-cacheline writes -> no RFO fetch).
// Block = 256 threads = 4 waves = 128 points.
// ---------------------------------------------------------------------------
__global__ __launch_bounds__(256) void gp_kernel(
    const __half* __restrict__ q,   // [B, S, 8]
    const __half* __restrict__ k,   // [B, S, 8]
    float* __restrict__ out)        // [B, S, S, 8]
{
  const int wave = threadIdx.x >> 6;
  const int lane = threadIdx.x & 63;
  const int h    = lane >> 5;                          // component half
  const int p    = blockIdx.x * 128 + wave * 32 + (lane & 31);  // b*S*S+n*S+m
  const int m    = p & (SEQ - 1);
  const int bn   = p >> 10;        // b*S + n  (block-uniform: 128 | 1024)
  const int b    = bn >> 10;

  H8 uq, uk;
  uq.f4 = *(const float4*)(q + (size_t)bn * 8);
  uk.f4 = *(const float4*)(k + ((size_t)b * SEQ + m) * 8);

  float qf[8], kf[8];
#pragma unroll
  for (int i = 0; i < 8; ++i) {
    qf[i] = __half2float(uq.h[i]);
    kf[i] = __half2float(uk.h[i]);
  }

  float o0 = 0.0f, o1 = 0.0f, o2 = 0.0f, o3 = 0.0f;
  if (h == 0) {
#pragma unroll
    for (int c = 0; c < 8; ++c) {
      o0 = fmaf(INV.s[0][c] * qf[INV.qi[0][c]], kf[INV.ki[0][c]], o0);
      o1 = fmaf(INV.s[1][c] * qf[INV.qi[1][c]], kf[INV.ki[1][c]], o1);
      o2 = fmaf(INV.s[2][c] * qf[INV.qi[2][c]], kf[INV.ki[2][c]], o2);
      o3 = fmaf(INV.s[3][c] * qf[INV.qi[3][c]], kf[INV.ki[3][c]], o3);
    }
  } else {
#pragma unroll
    for (int c = 0; c < 8; ++c) {
      o0 = fmaf(INV.s[4][c] * qf[INV.qi[4][c]], kf[INV.ki[4][c]], o0);
      o1 = fmaf(INV.s[5][c] * qf[INV.qi[5][c]], kf[INV.ki[5][c]], o1);
      o2 = fmaf(INV.s[6][c] * qf[INV.qi[6][c]], kf[INV.ki[6][c]], o2);
      o3 = fmaf(INV.s[7][c] * qf[INV.qi[7][c]], kf[INV.ki[7][c]], o3);
    }
  }

  *(float4*)(out + (size_t)p * 8 + h * 4) = make_float4(o0, o1, o2, o3);
}

// ---------------------------------------------------------------------------
extern "C" void kernel_launch(void* const* d_in, const int* in_sizes, int n_in,
                              void* d_out, int out_size, void* d_ws, size_t ws_size,
                              hipStream_t stream) {
  const float* x     = (const float*)d_in[0];
  const float* Wq    = (const float*)d_in[1];
  const float* bq    = (const float*)d_in[2];
  const float* Wk    = (const float*)d_in[3];
  const float* bk    = (const float*)d_in[4];
  const float* gamma = (const float*)d_in[5];
  const float* beta  = (const float*)d_in[6];

  __half* qbuf = (__half*)d_ws;
  __half* kbuf = qbuf + (size_t)BATCH * SEQ * 8;

  qk_kernel<<<SEQ, 256, 0, stream>>>(x, Wq, bq, Wk, bk, gamma, beta, qbuf, kbuf);

  const int points = BATCH * SEQ * SEQ;             // one point = 8 f32 outputs
  gp_kernel<<<points / 128, 256, 0, stream>>>(qbuf, kbuf, (float*)d_out);
}